// Round 5
// baseline (46.852 us; speedup 1.0000x reference)
//
#include <hip/hip_runtime.h>
#include <hip/hip_fp16.h>

#define INPUT_SIZE 128
#define NUM_REL 16

typedef int   i32x4 __attribute__((ext_vector_type(4)));
typedef float f32x4 __attribute__((ext_vector_type(4)));

// ---------------------------------------------------------------------------
// Kernel 1: per-node logit tables, SPLIT fp16 output.
//   Ls[n][r] = x[n] . att_weight[0:128, r]      (r = 0..15)
//   Ld[n][r] = x[n] . att_weight[128:256, r]
// 256 threads = 128 nodes/block (R2 config: 4 nodes x 4 rels per thread —
// best measured k1). w in LDS repacked swc[k][32]; ds_read_b128 per 4 rels,
// 8 unique addrs spanning all 32 banks -> conflict-free.
// ---------------------------------------------------------------------------
__global__ __launch_bounds__(256) void node_logits_kernel(
    const float* __restrict__ x,
    const float* __restrict__ w,      // (256,16) row-major
    __half* __restrict__ Ls,          // (num_nodes, 16) fp16
    __half* __restrict__ Ld,          // (num_nodes, 16) fp16
    int num_nodes)
{
    __shared__ float swc[128 * 32];   // swc[k*32 + r], 16 KB

    const int tid = threadIdx.x;

    // Stage + repack weights: swc[k][r] = r<16 ? w[k][r] : w[128+k][r-16]
    #pragma unroll
    for (int i = 0; i < 16; ++i) {
        const int idx = i * 256 + tid;         // 0..4095
        const int k = idx >> 5, r = idx & 31;
        swc[idx] = (r < 16) ? w[k * NUM_REL + r]
                            : w[(INPUT_SIZE + k) * NUM_REL + (r - 16)];
    }
    __syncthreads();

    const int ng = tid >> 3;                   // node group 0..31
    const int rg = tid & 7;                    // rel group  0..7 (0-3 src, 4-7 dst)
    const int node0 = blockIdx.x * 128 + ng * 4;
    const int r0 = rg * 4;

    const f32x4* xr[4];
    bool valid[4];
    #pragma unroll
    for (int n = 0; n < 4; ++n) {
        const int nn = node0 + n;
        valid[n] = (nn < num_nodes);
        xr[n] = (const f32x4*)(x + (size_t)(valid[n] ? nn : 0) * INPUT_SIZE);
    }

    float acc[4][4] = {};

    #pragma unroll 4
    for (int ks = 0; ks < 32; ++ks) {          // 4 k's per step
        f32x4 xv[4], wv[4];
        #pragma unroll
        for (int n = 0; n < 4; ++n) xv[n] = xr[n][ks];
        #pragma unroll
        for (int kk = 0; kk < 4; ++kk)
            wv[kk] = *(const f32x4*)&swc[(ks * 4 + kk) * 32 + r0];

        #pragma unroll
        for (int n = 0; n < 4; ++n) {
            #pragma unroll
            for (int c = 0; c < 4; ++c) {
                acc[n][0] += xv[n][c] * wv[c][0];
                acc[n][1] += xv[n][c] * wv[c][1];
                acc[n][2] += xv[n][c] * wv[c][2];
                acc[n][3] += xv[n][c] * wv[c][3];
            }
        }
    }

    __half* base = (rg < 4) ? Ls : Ld;
    const int rr = (rg & 3) * 4;
    #pragma unroll
    for (int n = 0; n < 4; ++n) {
        if (!valid[n]) continue;
        union { __half2 h2[2]; uint2 u; } pk;
        pk.h2[0] = __floats2half2_rn(acc[n][0], acc[n][1]);
        pk.h2[1] = __floats2half2_rn(acc[n][2], acc[n][3]);
        *(uint2*)(base + (size_t)(node0 + n) * NUM_REL + rr) = pk.u;   // 8B aligned
    }
}

// ---------------------------------------------------------------------------
// Pass A: src gathers only. Working set = Ls (1.6 MB) -> L2-resident.
// partial[e] = Ls[s[e]][t[e]] stored as raw fp16 (exact, no extra rounding).
// 8 edges/thread.
// ---------------------------------------------------------------------------
__global__ __launch_bounds__(256) void edge_src_kernel(
    const int* __restrict__ ei,       // (2, E) int32 (src half used)
    const int* __restrict__ et,       // (E,) int32
    const __half* __restrict__ Ls,    // (N, 16)
    __half* __restrict__ partial,     // (E,) fp16
    int num_edges)
{
    const int i = blockIdx.x * blockDim.x + threadIdx.x;   // octet index
    if (i * 8 >= num_edges) return;

    const i32x4* es = (const i32x4*)ei;
    const i32x4* tt = (const i32x4*)et;
    const i32x4 sa = es[2 * i], sb = es[2 * i + 1];
    const i32x4 ta = tt[2 * i], tb = tt[2 * i + 1];

    int s[8], t[8];
    #pragma unroll
    for (int j = 0; j < 4; ++j) {
        s[j] = sa[j]; s[4 + j] = sb[j];
        t[j] = ta[j]; t[4 + j] = tb[j];
    }

    union { __half h[8]; i32x4 v; } pk;
    #pragma unroll
    for (int j = 0; j < 8; ++j)
        pk.h[j] = Ls[(size_t)s[j] * NUM_REL + t[j]];

    ((i32x4*)partial)[i] = pk.v;                           // 16B coalesced store
}

// ---------------------------------------------------------------------------
// Pass B: dst gathers only. Working set = Ld (1.6 MB) -> L2-resident.
// score = partial + Ld[d][t]; sigmoid; clamp. 8 edges/thread.
// ---------------------------------------------------------------------------
__global__ __launch_bounds__(256) void edge_dst_kernel(
    const int* __restrict__ ei,       // (2, E) int32 (dst half used)
    const int* __restrict__ et,       // (E,) int32
    const __half* __restrict__ Ld,    // (N, 16)
    const __half* __restrict__ partial,
    float* __restrict__ out,
    int num_edges)
{
    const int i = blockIdx.x * blockDim.x + threadIdx.x;   // octet index
    if (i * 8 >= num_edges) return;

    const i32x4* ed = (const i32x4*)(ei + num_edges);
    const i32x4* tt = (const i32x4*)et;
    const i32x4 da = ed[2 * i], db = ed[2 * i + 1];
    const i32x4 ta = tt[2 * i], tb = tt[2 * i + 1];

    union { __half h[8]; i32x4 v; } pa;
    pa.v = ((const i32x4*)partial)[i];

    int d[8], t[8];
    #pragma unroll
    for (int j = 0; j < 4; ++j) {
        d[j] = da[j]; d[4 + j] = db[j];
        t[j] = ta[j]; t[4 + j] = tb[j];
    }

    __half hd[8];
    #pragma unroll
    for (int j = 0; j < 8; ++j)
        hd[j] = Ld[(size_t)d[j] * NUM_REL + t[j]];

    f32x4 r[2];
    #pragma unroll
    for (int j = 0; j < 8; ++j) {
        const float sc = __half2float(pa.h[j]) + __half2float(hd[j]);
        const float att = 1.f / (1.f + __expf(-sc));
        r[j >> 2][j & 3] = fminf(fmaxf(att, 1e-5f), 0.99999f);
    }
    f32x4* o = (f32x4*)out;
    o[2 * i]     = r[0];
    o[2 * i + 1] = r[1];
}

// Fallback: direct per-edge dot product in f32 (no workspace).
__global__ void edge_direct_kernel(const float* __restrict__ x,
                                   const float* __restrict__ w,
                                   const int* __restrict__ ei,
                                   const int* __restrict__ et,
                                   float* __restrict__ out,
                                   int num_edges) {
    const int e = blockIdx.x * blockDim.x + threadIdx.x;
    if (e >= num_edges) return;
    const int s = ei[e];
    const int d = ei[num_edges + e];
    const int t = et[e];
    const float* xs = x + (size_t)s * INPUT_SIZE;
    const float* xd = x + (size_t)d * INPUT_SIZE;
    float acc = 0.f;
    #pragma unroll 4
    for (int k = 0; k < INPUT_SIZE; ++k)
        acc += xs[k] * w[k * NUM_REL + t] + xd[k] * w[(INPUT_SIZE + k) * NUM_REL + t];
    const float att = 1.f / (1.f + __expf(-acc));
    out[e] = fminf(fmaxf(att, 1e-5f), 0.99999f);
}

extern "C" void kernel_launch(void* const* d_in, const int* in_sizes, int n_in,
                              void* d_out, int out_size, void* d_ws, size_t ws_size,
                              hipStream_t stream) {
    const float* x  = (const float*)d_in[0];   // (50000, 128) f32
    const float* w  = (const float*)d_in[1];   // (256, 16) f32
    const int*   ei = (const int*)d_in[2];     // (2, E) int32
    const int*   et = (const int*)d_in[3];     // (E,) int32
    float* out = (float*)d_out;

    const int num_nodes = in_sizes[0] / INPUT_SIZE;
    const int num_edges = in_sizes[3];

    const size_t tbl_bytes = (size_t)num_nodes * NUM_REL * sizeof(__half); // 1.6 MB
    const size_t par_bytes = (size_t)num_edges * sizeof(__half);           // 3.2 MB
    const size_t ws_needed = 2 * tbl_bytes + par_bytes;

    if (ws_size >= ws_needed && (num_edges & 7) == 0) {
        __half* Ls      = (__half*)d_ws;
        __half* Ld      = (__half*)((char*)d_ws + tbl_bytes);
        __half* partial = (__half*)((char*)d_ws + 2 * tbl_bytes);

        const int blocks1 = (num_nodes + 127) / 128;
        node_logits_kernel<<<blocks1, 256, 0, stream>>>(x, w, Ls, Ld, num_nodes);

        const int octs    = num_edges / 8;
        const int blocks2 = (octs + 255) / 256;
        edge_src_kernel<<<blocks2, 256, 0, stream>>>(ei, et, Ls, partial, num_edges);
        edge_dst_kernel<<<blocks2, 256, 0, stream>>>(ei, et, Ld, partial, out, num_edges);
    } else {
        const int blocks = (num_edges + 255) / 256;
        edge_direct_kernel<<<blocks, 256, 0, stream>>>(x, w, ei, et, out, num_edges);
    }
}

// Round 6
// 43.840 us; speedup vs baseline: 1.0687x; 1.0687x over previous
//
#include <hip/hip_runtime.h>
#include <hip/hip_fp16.h>

#define INPUT_SIZE 128
#define NUM_REL 16

typedef int   i32x4 __attribute__((ext_vector_type(4)));
typedef float f32x4 __attribute__((ext_vector_type(4)));

// ---------------------------------------------------------------------------
// Kernel 1: per-node logit tables, SPLIT fp16 output (unchanged from R5).
//   Ls[n][r] = x[n] . att_weight[0:128, r]      (r = 0..15)
//   Ld[n][r] = x[n] . att_weight[128:256, r]
// 256 threads = 128 nodes/block, 4 nodes x 4 rels per thread. w staged in LDS
// repacked swc[k][32]; ds_read_b128 per 4 rels, conflict-free.
// ---------------------------------------------------------------------------
__global__ __launch_bounds__(256) void node_logits_kernel(
    const float* __restrict__ x,
    const float* __restrict__ w,      // (256,16) row-major
    __half* __restrict__ Ls,          // (num_nodes, 16) fp16
    __half* __restrict__ Ld,          // (num_nodes, 16) fp16
    int num_nodes)
{
    __shared__ float swc[128 * 32];   // swc[k*32 + r], 16 KB

    const int tid = threadIdx.x;

    // Stage + repack weights: swc[k][r] = r<16 ? w[k][r] : w[128+k][r-16]
    #pragma unroll
    for (int i = 0; i < 16; ++i) {
        const int idx = i * 256 + tid;         // 0..4095
        const int k = idx >> 5, r = idx & 31;
        swc[idx] = (r < 16) ? w[k * NUM_REL + r]
                            : w[(INPUT_SIZE + k) * NUM_REL + (r - 16)];
    }
    __syncthreads();

    const int ng = tid >> 3;                   // node group 0..31
    const int rg = tid & 7;                    // rel group  0..7 (0-3 src, 4-7 dst)
    const int node0 = blockIdx.x * 128 + ng * 4;
    const int r0 = rg * 4;

    const f32x4* xr[4];
    bool valid[4];
    #pragma unroll
    for (int n = 0; n < 4; ++n) {
        const int nn = node0 + n;
        valid[n] = (nn < num_nodes);
        xr[n] = (const f32x4*)(x + (size_t)(valid[n] ? nn : 0) * INPUT_SIZE);
    }

    float acc[4][4] = {};

    #pragma unroll 4
    for (int ks = 0; ks < 32; ++ks) {          // 4 k's per step
        f32x4 xv[4], wv[4];
        #pragma unroll
        for (int n = 0; n < 4; ++n) xv[n] = xr[n][ks];
        #pragma unroll
        for (int kk = 0; kk < 4; ++kk)
            wv[kk] = *(const f32x4*)&swc[(ks * 4 + kk) * 32 + r0];

        #pragma unroll
        for (int n = 0; n < 4; ++n) {
            #pragma unroll
            for (int c = 0; c < 4; ++c) {
                acc[n][0] += xv[n][c] * wv[c][0];
                acc[n][1] += xv[n][c] * wv[c][1];
                acc[n][2] += xv[n][c] * wv[c][2];
                acc[n][3] += xv[n][c] * wv[c][3];
            }
        }
    }

    __half* base = (rg < 4) ? Ls : Ld;
    const int rr = (rg & 3) * 4;
    #pragma unroll
    for (int n = 0; n < 4; ++n) {
        if (!valid[n]) continue;
        union { __half2 h2[2]; uint2 u; } pk;
        pk.h2[0] = __floats2half2_rn(acc[n][0], acc[n][1]);
        pk.h2[1] = __floats2half2_rn(acc[n][2], acc[n][3]);
        *(uint2*)(base + (size_t)(node0 + n) * NUM_REL + rr) = pk.u;   // 8B aligned
    }
}

// ---------------------------------------------------------------------------
// Kernel 2: per-edge gather + sigmoid + clamp. 2 edges/thread.
// R6 change: occupancy. 800K threads (12.5K waves, ~49 waves/CU queued ->
// full 32-wave residency) vs R2-R5's 200K threads (12 waves/CU). Gathers are
// latency-bound; concurrency scales with resident waves.
// ---------------------------------------------------------------------------
__global__ __launch_bounds__(256) void edge_score_kernel(
    const int* __restrict__ ei,       // (2, E) int32
    const int* __restrict__ et,       // (E,) int32
    const __half* __restrict__ Ls,    // (N, 16)
    const __half* __restrict__ Ld,    // (N, 16)
    float* __restrict__ out,
    int num_edges)
{
    const int i = blockIdx.x * blockDim.x + threadIdx.x;   // pair index
    if (i * 2 >= num_edges) return;

    const int2 s2 = ((const int2*)ei)[i];
    const int2 d2 = ((const int2*)(ei + num_edges))[i];
    const int2 t2 = ((const int2*)et)[i];

    // 4 independent gathers in flight.
    const __half a0 = Ls[(size_t)s2.x * NUM_REL + t2.x];
    const __half a1 = Ls[(size_t)s2.y * NUM_REL + t2.y];
    const __half b0 = Ld[(size_t)d2.x * NUM_REL + t2.x];
    const __half b1 = Ld[(size_t)d2.y * NUM_REL + t2.y];

    const float sc0 = __half2float(a0) + __half2float(b0);
    const float sc1 = __half2float(a1) + __half2float(b1);
    const float r0 = fminf(fmaxf(1.f / (1.f + __expf(-sc0)), 1e-5f), 0.99999f);
    const float r1 = fminf(fmaxf(1.f / (1.f + __expf(-sc1)), 1e-5f), 0.99999f);

    ((float2*)out)[i] = make_float2(r0, r1);
}

// Fallback: direct per-edge dot product in f32 (no workspace).
__global__ void edge_direct_kernel(const float* __restrict__ x,
                                   const float* __restrict__ w,
                                   const int* __restrict__ ei,
                                   const int* __restrict__ et,
                                   float* __restrict__ out,
                                   int num_edges) {
    const int e = blockIdx.x * blockDim.x + threadIdx.x;
    if (e >= num_edges) return;
    const int s = ei[e];
    const int d = ei[num_edges + e];
    const int t = et[e];
    const float* xs = x + (size_t)s * INPUT_SIZE;
    const float* xd = x + (size_t)d * INPUT_SIZE;
    float acc = 0.f;
    #pragma unroll 4
    for (int k = 0; k < INPUT_SIZE; ++k)
        acc += xs[k] * w[k * NUM_REL + t] + xd[k] * w[(INPUT_SIZE + k) * NUM_REL + t];
    const float att = 1.f / (1.f + __expf(-acc));
    out[e] = fminf(fmaxf(att, 1e-5f), 0.99999f);
}

extern "C" void kernel_launch(void* const* d_in, const int* in_sizes, int n_in,
                              void* d_out, int out_size, void* d_ws, size_t ws_size,
                              hipStream_t stream) {
    const float* x  = (const float*)d_in[0];   // (50000, 128) f32
    const float* w  = (const float*)d_in[1];   // (256, 16) f32
    const int*   ei = (const int*)d_in[2];     // (2, E) int32
    const int*   et = (const int*)d_in[3];     // (E,) int32
    float* out = (float*)d_out;

    const int num_nodes = in_sizes[0] / INPUT_SIZE;
    const int num_edges = in_sizes[3];

    const size_t tbl_bytes = (size_t)num_nodes * NUM_REL * sizeof(__half); // 1.6 MB
    const size_t ws_needed = 2 * tbl_bytes;

    if (ws_size >= ws_needed && (num_edges & 1) == 0) {
        __half* Ls = (__half*)d_ws;
        __half* Ld = (__half*)((char*)d_ws + tbl_bytes);

        const int blocks1 = (num_nodes + 127) / 128;
        node_logits_kernel<<<blocks1, 256, 0, stream>>>(x, w, Ls, Ld, num_nodes);

        const int pairs   = num_edges / 2;
        const int blocks2 = (pairs + 255) / 256;
        edge_score_kernel<<<blocks2, 256, 0, stream>>>(ei, et, Ls, Ld, out, num_edges);
    } else {
        const int blocks = (num_edges + 255) / 256;
        edge_direct_kernel<<<blocks, 256, 0, stream>>>(x, w, ei, et, out, num_edges);
    }
}